// Round 3
// baseline (375.610 us; speedup 1.0000x reference)
//
#include <hip/hip_runtime.h>

#define NB 2048
#define S_ 200
#define C_ 25
#define H_ 8
#define WROWS 208        // padded row count for packed X rows
#define STR 36           // dword stride of packed rows (multiple of 4 -> b128-aligned)
#define NSTRIP 13        // ceil(200/16) t-strips
#define NSTILE 13        // ceil(200/16) s-tiles
#define NPAIR 7          // ceil(13/2) strip pairs (K=32 each)
#define XDS 28           // x_del float stride in reused LDS (16B-aligned rows)
#define WFRAG (13 * 64 * 4)   // 3328 dwords per W fragment plane

typedef __bf16   bf16x8 __attribute__((ext_vector_type(8)));
typedef float    f32x4  __attribute__((ext_vector_type(4)));
typedef unsigned uint4v __attribute__((ext_vector_type(4)));

struct Frag { bf16x8 hi, lo; };

__device__ __forceinline__ unsigned short f2bf(float f) {
    unsigned u = __builtin_bit_cast(unsigned, f);
    return (unsigned short)((u + 0x7FFFu + ((u >> 16) & 1u)) >> 16);
}
__device__ __forceinline__ float bfh2f(unsigned short h) {
    return __builtin_bit_cast(float, (unsigned)h << 16);
}
// pack one f32 into (hi bf16 | lo bf16 << 16)
__device__ __forceinline__ unsigned pack_hl(float v) {
    unsigned short h = f2bf(v);
    unsigned short l = f2bf(v - bfh2f(h));
    return (unsigned)h | ((unsigned)l << 16);
}
__device__ __forceinline__ unsigned hi_pair(unsigned d0, unsigned d1) {
    return (d0 & 0xFFFFu) | (d1 << 16);
}
__device__ __forceinline__ unsigned lo_pair(unsigned d0, unsigned d1) {
    return (d0 >> 16) | (d1 & 0xFFFF0000u);
}
__device__ __forceinline__ Frag build_frag8(uint4v d0, uint4v d1) {
    uint4v h, l;
    h.x = hi_pair(d0.x, d0.y); h.y = hi_pair(d0.z, d0.w);
    h.z = hi_pair(d1.x, d1.y); h.w = hi_pair(d1.z, d1.w);
    l.x = lo_pair(d0.x, d0.y); l.y = lo_pair(d0.z, d0.w);
    l.z = lo_pair(d1.x, d1.y); l.w = lo_pair(d1.z, d1.w);
    Frag f;
    f.hi = __builtin_bit_cast(bf16x8, h);
    f.lo = __builtin_bit_cast(bf16x8, l);
    return f;
}
__device__ __forceinline__ bf16x8 build_hi8(uint4v d0, uint4v d1) {
    uint4v h;
    h.x = hi_pair(d0.x, d0.y); h.y = hi_pair(d0.z, d0.w);
    h.z = hi_pair(d1.x, d1.y); h.w = hi_pair(d1.z, d1.w);
    return __builtin_bit_cast(bf16x8, h);
}
__device__ __forceinline__ f32x4 mfma16(bf16x8 a, bf16x8 b, f32x4 c) {
    return __builtin_amdgcn_mfma_f32_16x16x32_bf16(a, b, c, 0, 0, 0);
}
// split-precision D += A*B (drop lo*lo term)
__device__ __forceinline__ f32x4 mfma_split(const Frag& a, const Frag& b, f32x4 c) {
    c = mfma16(a.hi, b.hi, c);
    c = mfma16(a.hi, b.lo, c);
    c = mfma16(a.lo, b.hi, c);
    return c;
}
// raw transcendentals: v_exp_f32 is 2^x, v_log_f32 is log2(x)
__device__ __forceinline__ float fexp2(float x) {
    float r; asm("v_exp_f32 %0, %1" : "=v"(r) : "v"(x)); return r;
}
__device__ __forceinline__ float flog2(float x) {
    float r; asm("v_log_f32 %0, %1" : "=v"(r) : "v"(x)); return r;
}
// pack two f32 -> (bf16(lo) | bf16(hi)<<16), RNE (no builtin on gfx950)
__device__ __forceinline__ unsigned cvt_pk_bf16(float vlo, float vhi) {
    unsigned r; asm("v_cvt_pk_bf16_f32 %0, %1, %2" : "=v"(r) : "v"(vlo), "v"(vhi)); return r;
}
__device__ __forceinline__ float lo16f(unsigned p) { return __builtin_bit_cast(float, p << 16); }
__device__ __forceinline__ float hi16f(unsigned p) { return __builtin_bit_cast(float, p & 0xFFFF0000u); }
// pack two f32 into two per-value (hi|lo<<16) dwords via cvt_pk (cheaper than 2x pack_hl)
__device__ __forceinline__ void pack_hl2(float v0, float v1, unsigned& d0, unsigned& d1) {
    unsigned hp = cvt_pk_bf16(v0, v1);
    float r0 = v0 - lo16f(hp);
    float r1 = v1 - hi16f(hp);
    unsigned lp = cvt_pk_bf16(r0, r1);
    d0 = (hp & 0xFFFFu) | (lp << 16);
    d1 = (hp >> 16) | (lp & 0xFFFF0000u);
}

// In-register MFMA C-layout (rows on quads/regs) -> A-layout (k on quads) transpose.
__device__ __forceinline__ void xpose_quads(unsigned& a0, unsigned& a1,
                                            unsigned& b0, unsigned& b1) {
    asm("v_permlane32_swap_b32 %0, %1" : "+v"(a0), "+v"(b0));
    asm("v_permlane32_swap_b32 %0, %1" : "+v"(a1), "+v"(b1));
    asm("v_permlane16_swap_b32 %0, %1" : "+v"(a0), "+v"(b0));
    asm("v_permlane16_swap_b32 %0, %1" : "+v"(a1), "+v"(b1));
}

// ---------- prep kernel: W fragment planes (pre-scaled by log2e) + A^2, A^4 ----------
__global__ void prep_w_kernel(const float* __restrict__ delay_W,
                              const float* __restrict__ A_W,
                              unsigned* __restrict__ ws) {
    const float LOG2E = 1.44269504088896340736f;
    unsigned* Whi = ws;
    unsigned* Wlo = ws + WFRAG;
    for (int idx = blockIdx.x * 256 + threadIdx.x; idx < WFRAG; idx += gridDim.x * 256) {
        int d = idx & 3, lane = (idx >> 2) & 63, sv = idx >> 8;
        int q = lane >> 4, nn = lane & 15;
        int s  = sv * 16 + nn;
        int c0 = q * 8 + 2 * d;
        float v0 = (s < S_ && c0     < C_) ? delay_W[s * C_ + c0]     * LOG2E : 0.f;
        float v1 = (s < S_ && c0 + 1 < C_) ? delay_W[s * C_ + c0 + 1] * LOG2E : 0.f;
        unsigned short h0 = f2bf(v0), h1 = f2bf(v1);
        unsigned short l0 = f2bf(v0 - bfh2f(h0)), l1 = f2bf(v1 - bfh2f(h1));
        Whi[idx] = (unsigned)h0 | ((unsigned)h1 << 16);
        Wlo[idx] = (unsigned)l0 | ((unsigned)l1 << 16);
    }
    // A^2 and A^4 for the 4-step parallel recurrence
    __shared__ float A2s[64];
    if (blockIdx.x == 0) {
        float* A2g = (float*)(ws + 2 * WFRAG);
        float* A4g = (float*)(ws + 2 * WFRAG + 64);
        const int i = threadIdx.x >> 3, j = threadIdx.x & 7;
        if (threadIdx.x < 64) {
            float s = 0.f;
            for (int k = 0; k < 8; ++k) s = fmaf(A_W[i * 8 + k], A_W[k * 8 + j], s);
            A2s[threadIdx.x] = s; A2g[threadIdx.x] = s;
        }
        __syncthreads();
        if (threadIdx.x < 64) {
            float s = 0.f;
            for (int k = 0; k < 8; ++k) s = fmaf(A2s[i * 8 + k], A2s[k * 8 + j], s);
            A4g[threadIdx.x] = s;
        }
    }
}

// ---------- main kernel: one block per batch ----------
__global__ __launch_bounds__(256, 5) void ssm_syn_delay_kernel(
    const float* __restrict__ x,       const unsigned* __restrict__ ws,
    const float* __restrict__ delay_b, const float* __restrict__ U_W,
    const float* __restrict__ U_b,     const float* __restrict__ A_W,
    const float* __restrict__ B_W,     const float* __restrict__ B_b,
    const float* __restrict__ out_W,   const float* __restrict__ out_b,
    float* __restrict__ out)
{
    // 31,616 B total -> 5 blocks/CU
    __shared__ __align__(16) unsigned X32[WROWS * STR]; // 29,952 B; later aliased by x_del + p buffers
    __shared__ __align__(16) float lsed[WROWS];         //    832 B (log2-domain lse)
    __shared__ __align__(16) float dbs_l[WROWS];        //    832 B (delay_b * log2e; -inf pad)

    const int tid  = threadIdx.x;
    const int wid  = tid >> 6;
    const int lane = tid & 63;
    const int q    = lane >> 4;     // quad 0..3
    const int n    = lane & 15;     // col-lane 0..15
    const int b    = blockIdx.x;
    const float* xb = x + (size_t)b * (S_ * C_);
    const unsigned* Whi = ws;
    const unsigned* Wlo = ws + WFRAG;
    const float* A2g = (const float*)(ws + 2 * WFRAG);
    const float* A4g = (const float*)(ws + 2 * WFRAG + 64);

    // ---- Phase 0: stage packed x rows (vectorized, cvt_pk) + delay_b into LDS ----
    for (int i = tid; i < WROWS * 9; i += 256) {
        int r = i / 9, cg = i - r * 9;        // cg: group of 4 dwords in the 36-dword row
        f32x4 v = {0.f, 0.f, 0.f, 0.f};
        if (r < S_) {
            if (cg < 6)       __builtin_memcpy(&v, &xb[r * C_ + cg * 4], 16); // c 0..23
            else if (cg == 6) v[0] = xb[r * C_ + 24];                          // c 24 (tail)
        }
        unsigned e0, e1, e2, e3;
        pack_hl2(v[0], v[1], e0, e1);
        pack_hl2(v[2], v[3], e2, e3);
        uint4v p = {e0, e1, e2, e3};
        *(uint4v*)&X32[r * STR + cg * 4] = p;
    }
    for (int i = tid; i < WROWS; i += 256)
        dbs_l[i] = (i < S_) ? delay_b[i] * 1.44269504088896340736f : -1e30f;
    __syncthreads();

    // ---- Pass 1: lse[t] (log2 domain), sv-outer. Wave owns strips wid, wid+4, wid+8, wid+12 ----
    {
        Frag fa[4];
        f32x4 rs[4];
#pragma unroll
        for (int k = 0; k < 4; ++k) {
            rs[k] = f32x4{0.f, 0.f, 0.f, 0.f};
            const int st = wid + 4 * k;
            if (st < NSTRIP) {
                const uint4v* xp = (const uint4v*)&X32[(st * 16 + n) * STR + q * 8];
                fa[k] = build_frag8(xp[0], xp[1]);   // A[m=t][k=c]
            }
        }
        for (int sv = 0; sv < NSTILE; ++sv) {
            Frag fb;                                 // B[k=c][n=s], pre-laid-out fragments
            fb.hi = __builtin_bit_cast(bf16x8, *(const uint4v*)&Whi[(sv * 64 + lane) * 4]);
            fb.lo = __builtin_bit_cast(bf16x8, *(const uint4v*)&Wlo[(sv * 64 + lane) * 4]);
            const float dbv = dbs_l[sv * 16 + n];    // = -1e30 for padded s -> exp2 = 0
#pragma unroll
            for (int k = 0; k < 4; ++k) {
                if (wid + 4 * k >= NSTRIP) continue; // wave-uniform
                f32x4 L = {0.f, 0.f, 0.f, 0.f};
                L = mfma_split(fa[k], fb, L);
                rs[k][0] += fexp2(L[0] + dbv);
                rs[k][1] += fexp2(L[1] + dbv);
                rs[k][2] += fexp2(L[2] + dbv);
                rs[k][3] += fexp2(L[3] + dbv);
            }
        }
#pragma unroll
        for (int k = 0; k < 4; ++k) {
            const int st = wid + 4 * k;
            if (st >= NSTRIP) continue;
            float r0 = rs[k][0], r1 = rs[k][1], r2 = rs[k][2], r3 = rs[k][3];
#pragma unroll
            for (int off = 1; off < 16; off <<= 1) {
                r0 += __shfl_xor(r0, off);
                r1 += __shfl_xor(r1, off);
                r2 += __shfl_xor(r2, off);
                r3 += __shfl_xor(r3, off);
            }
            if (n < 4) {
                float v = (n == 0) ? r0 : (n == 1) ? r1 : (n == 2) ? r2 : r3;
                lsed[st * 16 + q * 4 + n] = flog2(v);
            }
        }
    }
    __syncthreads();

    // ---- Pass 2: x_del = P^T X via MFMA, strip pairs; P transpose fully in-register ----
    f32x4 acc[4][2];
#pragma unroll
    for (int i = 0; i < 4; ++i)
#pragma unroll
        for (int j = 0; j < 2; ++j) acc[i][j] = f32x4{0.f, 0.f, 0.f, 0.f};

    // hoist this wave's W fragments + delay-bias values across the whole pair loop
    Frag fbs[4];
    float dbv4[4] = {0.f, 0.f, 0.f, 0.f};
#pragma unroll
    for (int si = 0; si < 4; ++si) {
        const int sv = wid + 4 * si;
        if (sv < NSTILE) {
            fbs[si].hi = __builtin_bit_cast(bf16x8, *(const uint4v*)&Whi[(sv * 64 + lane) * 4]);
            fbs[si].lo = __builtin_bit_cast(bf16x8, *(const uint4v*)&Wlo[(sv * 64 + lane) * 4]);
            dbv4[si] = dbs_l[sv * 16 + n];
        }
    }

    for (int pair = 0; pair < NPAIR; ++pair) {
        const int sA = 2 * pair, sB = sA + 1;
        const bool bval = (sB < NSTRIP);
        const uint4v* xpA = (const uint4v*)&X32[(sA * 16 + n) * STR + q * 8];
        Frag faA = build_frag8(xpA[0], xpA[1]);
        Frag faB;
        if (bval) {
            const uint4v* xpB = (const uint4v*)&X32[(sB * 16 + n) * STR + q * 8];
            faB = build_frag8(xpB[0], xpB[1]);
        }
        f32x4 lseA = *(const f32x4*)&lsed[sA * 16 + q * 4];
        f32x4 lseB = bval ? *(const f32x4*)&lsed[sB * 16 + q * 4] : f32x4{0,0,0,0};
        // B2 frags (hi only): B[k=t][n=c], t = pair*32 + q*8 + j
        bf16x8 b2h[2];
#pragma unroll
        for (int ct = 0; ct < 2; ++ct) {
            const int c = ct * 16 + n;
            uint4v d0, d1;
#pragma unroll
            for (int j = 0; j < 4; ++j) {
                int t2 = pair * 32 + q * 8 + j;
                ((unsigned*)&d0)[j] = (t2 < WROWS) ? X32[t2 * STR + c] : 0u;
            }
#pragma unroll
            for (int j = 0; j < 4; ++j) {
                int t2 = pair * 32 + q * 8 + 4 + j;
                ((unsigned*)&d1)[j] = (t2 < WROWS) ? X32[t2 * STR + c] : 0u;
            }
            b2h[ct] = build_hi8(d0, d1);
        }

#pragma unroll
        for (int si = 0; si < 4; ++si) {
            const int sv = wid + 4 * si;
            if (sv >= NSTILE) continue;          // wave-uniform branch
            const float dbv = dbv4[si];
            // strip A logits -> P (hi/lo packed pairs, C-layout)
            unsigned pA0, pA1, qA0, qA1;
            {
                f32x4 L = {0.f, 0.f, 0.f, 0.f};
                L = mfma_split(faA, fbs[si], L);
                float e0 = fexp2(L[0] + dbv - lseA[0]);
                float e1 = fexp2(L[1] + dbv - lseA[1]);
                float e2 = fexp2(L[2] + dbv - lseA[2]);
                float e3 = fexp2(L[3] + dbv - lseA[3]);
                pA0 = cvt_pk_bf16(e0, e1);
                pA1 = cvt_pk_bf16(e2, e3);
                qA0 = cvt_pk_bf16(e0 - lo16f(pA0), e1 - hi16f(pA0));
                qA1 = cvt_pk_bf16(e2 - lo16f(pA1), e3 - hi16f(pA1));
            }
            // strip B (or zeros)
            unsigned pB0 = 0u, pB1 = 0u, qB0 = 0u, qB1 = 0u;
            if (bval) {
                f32x4 L = {0.f, 0.f, 0.f, 0.f};
                L = mfma_split(faB, fbs[si], L);
                float e0 = fexp2(L[0] + dbv - lseB[0]);
                float e1 = fexp2(L[1] + dbv - lseB[1]);
                float e2 = fexp2(L[2] + dbv - lseB[2]);
                float e3 = fexp2(L[3] + dbv - lseB[3]);
                pB0 = cvt_pk_bf16(e0, e1);
                pB1 = cvt_pk_bf16(e2, e3);
                qB0 = cvt_pk_bf16(e0 - lo16f(pB0), e1 - hi16f(pB0));
                qB1 = cvt_pk_bf16(e2 - lo16f(pB1), e3 - hi16f(pB1));
            }
            // in-register transpose to A-layout: A[m=s][k=t], k = q*8 + j
            xpose_quads(pA0, pA1, pB0, pB1);
            xpose_quads(qA0, qA1, qB0, qB1);
            uint4v hv = {pA0, pA1, pB0, pB1};
            uint4v lv = {qA0, qA1, qB0, qB1};
            bf16x8 a2h = __builtin_bit_cast(bf16x8, hv);
            bf16x8 a2l = __builtin_bit_cast(bf16x8, lv);
#pragma unroll
            for (int ct = 0; ct < 2; ++ct) {
                f32x4 c4 = acc[si][ct];
                c4 = mfma16(a2h, b2h[ct], c4);
                c4 = mfma16(a2l, b2h[ct], c4);
                acc[si][ct] = c4;
            }
        }
    }
    __syncthreads();   // all X32 reads done; safe to alias

    // ---- store x_del into reused LDS (float, stride XDS=28, 16B-aligned rows) ----
    float* xdelf = (float*)&X32[0];
    float* p_s   = (float*)&X32[5696];   // 200*8 floats, after x_del's 200*28=5600
#pragma unroll
    for (int si = 0; si < 4; ++si) {
        const int sv = wid + 4 * si;
        if (sv >= NSTILE) continue;
#pragma unroll
        for (int ct = 0; ct < 2; ++ct) {
            const int c = ct * 16 + n;
            if (c < C_) {
#pragma unroll
                for (int r = 0; r < 4; ++r) {
                    const int s = sv * 16 + q * 4 + r;
                    if (s < S_) xdelf[s * XDS + c] = acc[si][ct][r];
                }
            }
        }
    }
    __syncthreads();

    // ---- u / bgate epilogue: thread s owns output timestep s (b128 x_del reads) ----
    if (tid < S_) {
        const int s = tid;
        float a[24];
        const f32x4* ar = (const f32x4*)&xdelf[s * XDS];
#pragma unroll
        for (int k = 0; k < 6; ++k) *(f32x4*)&a[k * 4] = ar[k];
        float a24 = xdelf[s * XDS + 24];
#pragma unroll
        for (int h = 0; h < H_; ++h) {
            float uu = fmaf(a24, U_W[h * C_ + 24], U_b[h]);
            float bb = fmaf(a24, B_W[h * C_ + 24], B_b[h]);
#pragma unroll
            for (int i = 0; i < 24; ++i) {
                uu = fmaf(a[i], U_W[h * C_ + i], uu);
                bb = fmaf(a[i], B_W[h * C_ + i], bb);
            }
            float sg_ = 1.0f / (1.0f + __expf(-bb));
            p_s[s * H_ + h] = uu * sg_;
        }
    }
    __syncthreads();

    // ---- linear recurrence h_s = A h_{s-1} + p_s via 4-step parallel prefix ----
    float* p1 = xdelf;                   // alias: xdelf dead after u/bgate
    float* p2 = xdelf + S_ * H_;
    for (int i2 = tid; i2 < S_ * H_; i2 += 256) {
        const int s = i2 >> 3, i = i2 & 7;
        float v = p_s[i2];
        if (s > 0) {
            const float* pm = &p_s[(s - 1) * H_];
#pragma unroll
            for (int j = 0; j < H_; ++j) v = fmaf(A_W[i * H_ + j], pm[j], v);
        }
        p1[i2] = v;
    }
    __syncthreads();
    for (int i2 = tid; i2 < S_ * H_; i2 += 256) {
        const int s = i2 >> 3, i = i2 & 7;
        float v = p1[i2];
        if (s > 1) {
            const float* pm = &p1[(s - 2) * H_];
#pragma unroll
            for (int j = 0; j < H_; ++j) v = fmaf(A2g[i * H_ + j], pm[j], v);
        }
        p2[i2] = v;
    }
    __syncthreads();
    // 4 independent chains (s mod 4) of 50 steps each; 32 lanes of wave 0
    if (tid < 32) {
        const int r = tid >> 3, i = tid & 7;
        float A4r[H_];
#pragma unroll
        for (int j = 0; j < H_; ++j) A4r[j] = A4g[i * H_ + j];
        float h = 0.f;
        for (int k = 0; k < 50; ++k) {
            const int s = 4 * k + r;
            float v = p2[s * H_ + i];
#pragma unroll
            for (int j = 0; j < H_; ++j) v = fmaf(A4r[j], __shfl(h, j, 8), v);
            h = v;
            p_s[s * H_ + i] = h;
        }
    }
    __syncthreads();

    // ---- out[b,s,c] = hs[s]·out_W[c,:] + out_b[c] (vectorized loads) ----
    float* ob_ptr = out + (size_t)b * (S_ * C_);
    for (int i = tid; i < S_ * C_; i += 256) {
        int s = i / C_, c = i - s * C_;
        const f32x4* pr = (const f32x4*)&p_s[s * H_];
        const f32x4* wr = (const f32x4*)&out_W[c * H_];
        f32x4 h0 = pr[0], h1 = pr[1];
        f32x4 w0 = wr[0], w1 = wr[1];
        float v = out_b[c];
        v = fmaf(h0[0], w0[0], v);
        v = fmaf(h0[1], w0[1], v);
        v = fmaf(h0[2], w0[2], v);
        v = fmaf(h0[3], w0[3], v);
        v = fmaf(h1[0], w1[0], v);
        v = fmaf(h1[1], w1[1], v);
        v = fmaf(h1[2], w1[2], v);
        v = fmaf(h1[3], w1[3], v);
        ob_ptr[i] = v;
    }
}

extern "C" void kernel_launch(void* const* d_in, const int* in_sizes, int n_in,
                              void* d_out, int out_size, void* d_ws, size_t ws_size,
                              hipStream_t stream) {
    const float* x       = (const float*)d_in[0];
    const float* delay_W = (const float*)d_in[1];
    const float* delay_b = (const float*)d_in[2];
    const float* U_W     = (const float*)d_in[3];
    const float* U_b     = (const float*)d_in[4];
    const float* A_W     = (const float*)d_in[5];
    const float* B_W     = (const float*)d_in[6];
    const float* B_b     = (const float*)d_in[7];
    const float* out_W   = (const float*)d_in[8];
    const float* out_b   = (const float*)d_in[9];
    float* out = (float*)d_out;
    unsigned* ws = (unsigned*)d_ws;   // (2*3328 + 128) dwords = 27,136 B

    prep_w_kernel<<<4, 256, 0, stream>>>(delay_W, A_W, ws);
    ssm_syn_delay_kernel<<<NB, 256, 0, stream>>>(
        x, ws, delay_b, U_W, U_b, A_W, B_W, B_b, out_W, out_b, out);
}

// Round 5
// 235.007 us; speedup vs baseline: 1.5983x; 1.5983x over previous
//
#include <hip/hip_runtime.h>

#define NB 2048
#define S_ 200
#define C_ 25
#define H_ 8
#define WROWS 208        // padded row count for packed X rows
#define STR 36           // dword stride of packed rows (multiple of 4 -> b128-aligned)
#define NSTRIP 13        // ceil(200/16) t-strips
#define NSTILE 13        // ceil(200/16) s-tiles
#define NPAIR 7          // ceil(13/2) strip pairs (K=32 each)
#define XDS 28           // x_del float stride in reused LDS (16B-aligned rows)
#define WFRAG (13 * 64 * 4)   // 3328 dwords per W fragment plane

typedef __bf16   bf16x8 __attribute__((ext_vector_type(8)));
typedef float    f32x4  __attribute__((ext_vector_type(4)));
typedef unsigned uint4v __attribute__((ext_vector_type(4)));

struct Frag { bf16x8 hi, lo; };

__device__ __forceinline__ unsigned short f2bf(float f) {
    unsigned u = __builtin_bit_cast(unsigned, f);
    return (unsigned short)((u + 0x7FFFu + ((u >> 16) & 1u)) >> 16);
}
__device__ __forceinline__ float bfh2f(unsigned short h) {
    return __builtin_bit_cast(float, (unsigned)h << 16);
}
// pack one f32 into (hi bf16 | lo bf16 << 16)
__device__ __forceinline__ unsigned pack_hl(float v) {
    unsigned short h = f2bf(v);
    unsigned short l = f2bf(v - bfh2f(h));
    return (unsigned)h | ((unsigned)l << 16);
}
__device__ __forceinline__ unsigned hi_pair(unsigned d0, unsigned d1) {
    return (d0 & 0xFFFFu) | (d1 << 16);
}
__device__ __forceinline__ unsigned lo_pair(unsigned d0, unsigned d1) {
    return (d0 >> 16) | (d1 & 0xFFFF0000u);
}
__device__ __forceinline__ Frag build_frag8(uint4v d0, uint4v d1) {
    uint4v h, l;
    h.x = hi_pair(d0.x, d0.y); h.y = hi_pair(d0.z, d0.w);
    h.z = hi_pair(d1.x, d1.y); h.w = hi_pair(d1.z, d1.w);
    l.x = lo_pair(d0.x, d0.y); l.y = lo_pair(d0.z, d0.w);
    l.z = lo_pair(d1.x, d1.y); l.w = lo_pair(d1.z, d1.w);
    Frag f;
    f.hi = __builtin_bit_cast(bf16x8, h);
    f.lo = __builtin_bit_cast(bf16x8, l);
    return f;
}
__device__ __forceinline__ bf16x8 build_hi8(uint4v d0, uint4v d1) {
    uint4v h;
    h.x = hi_pair(d0.x, d0.y); h.y = hi_pair(d0.z, d0.w);
    h.z = hi_pair(d1.x, d1.y); h.w = hi_pair(d1.z, d1.w);
    return __builtin_bit_cast(bf16x8, h);
}
__device__ __forceinline__ f32x4 mfma16(bf16x8 a, bf16x8 b, f32x4 c) {
    return __builtin_amdgcn_mfma_f32_16x16x32_bf16(a, b, c, 0, 0, 0);
}
// split-precision D += A*B (drop lo*lo term)
__device__ __forceinline__ f32x4 mfma_split(const Frag& a, const Frag& b, f32x4 c) {
    c = mfma16(a.hi, b.hi, c);
    c = mfma16(a.hi, b.lo, c);
    c = mfma16(a.lo, b.hi, c);
    return c;
}
// raw transcendentals: v_exp_f32 is 2^x, v_log_f32 is log2(x)
__device__ __forceinline__ float fexp2(float x) {
    float r; asm("v_exp_f32 %0, %1" : "=v"(r) : "v"(x)); return r;
}
__device__ __forceinline__ float flog2(float x) {
    float r; asm("v_log_f32 %0, %1" : "=v"(r) : "v"(x)); return r;
}
// pack two f32 -> (bf16(lo) | bf16(hi)<<16), RNE (no builtin on gfx950)
__device__ __forceinline__ unsigned cvt_pk_bf16(float vlo, float vhi) {
    unsigned r; asm("v_cvt_pk_bf16_f32 %0, %1, %2" : "=v"(r) : "v"(vlo), "v"(vhi)); return r;
}
__device__ __forceinline__ float lo16f(unsigned p) { return __builtin_bit_cast(float, p << 16); }
__device__ __forceinline__ float hi16f(unsigned p) { return __builtin_bit_cast(float, p & 0xFFFF0000u); }
// pack two f32 into two per-value (hi|lo<<16) dwords via cvt_pk (cheaper than 2x pack_hl)
__device__ __forceinline__ void pack_hl2(float v0, float v1, unsigned& d0, unsigned& d1) {
    unsigned hp = cvt_pk_bf16(v0, v1);
    float r0 = v0 - lo16f(hp);
    float r1 = v1 - hi16f(hp);
    unsigned lp = cvt_pk_bf16(r0, r1);
    d0 = (hp & 0xFFFFu) | (lp << 16);
    d1 = (hp >> 16) | (lp & 0xFFFF0000u);
}

// In-register MFMA C-layout (rows on quads/regs) -> A-layout (k on quads) transpose.
__device__ __forceinline__ void xpose_quads(unsigned& a0, unsigned& a1,
                                            unsigned& b0, unsigned& b1) {
    asm("v_permlane32_swap_b32 %0, %1" : "+v"(a0), "+v"(b0));
    asm("v_permlane32_swap_b32 %0, %1" : "+v"(a1), "+v"(b1));
    asm("v_permlane16_swap_b32 %0, %1" : "+v"(a0), "+v"(b0));
    asm("v_permlane16_swap_b32 %0, %1" : "+v"(a1), "+v"(b1));
}

// ---------- prep kernel: W fragment planes (pre-scaled by log2e) + A^2, A^4 ----------
__global__ void prep_w_kernel(const float* __restrict__ delay_W,
                              const float* __restrict__ A_W,
                              unsigned* __restrict__ ws) {
    const float LOG2E = 1.44269504088896340736f;
    unsigned* Whi = ws;
    unsigned* Wlo = ws + WFRAG;
    for (int idx = blockIdx.x * 256 + threadIdx.x; idx < WFRAG; idx += gridDim.x * 256) {
        int d = idx & 3, lane = (idx >> 2) & 63, sv = idx >> 8;
        int q = lane >> 4, nn = lane & 15;
        int s  = sv * 16 + nn;
        int c0 = q * 8 + 2 * d;
        float v0 = (s < S_ && c0     < C_) ? delay_W[s * C_ + c0]     * LOG2E : 0.f;
        float v1 = (s < S_ && c0 + 1 < C_) ? delay_W[s * C_ + c0 + 1] * LOG2E : 0.f;
        unsigned short h0 = f2bf(v0), h1 = f2bf(v1);
        unsigned short l0 = f2bf(v0 - bfh2f(h0)), l1 = f2bf(v1 - bfh2f(h1));
        Whi[idx] = (unsigned)h0 | ((unsigned)h1 << 16);
        Wlo[idx] = (unsigned)l0 | ((unsigned)l1 << 16);
    }
    // A^2 and A^4 for the 4-step parallel recurrence
    __shared__ float A2s[64];
    if (blockIdx.x == 0) {
        float* A2g = (float*)(ws + 2 * WFRAG);
        float* A4g = (float*)(ws + 2 * WFRAG + 64);
        const int i = threadIdx.x >> 3, j = threadIdx.x & 7;
        if (threadIdx.x < 64) {
            float s = 0.f;
            for (int k = 0; k < 8; ++k) s = fmaf(A_W[i * 8 + k], A_W[k * 8 + j], s);
            A2s[threadIdx.x] = s; A2g[threadIdx.x] = s;
        }
        __syncthreads();
        if (threadIdx.x < 64) {
            float s = 0.f;
            for (int k = 0; k < 8; ++k) s = fmaf(A2s[i * 8 + k], A2s[k * 8 + j], s);
            A4g[threadIdx.x] = s;
        }
    }
}

// ---------- main kernel: one block per batch ----------
__global__ __launch_bounds__(256, 5) void ssm_syn_delay_kernel(
    const float* __restrict__ x,       const unsigned* __restrict__ ws,
    const float* __restrict__ delay_b, const float* __restrict__ U_W,
    const float* __restrict__ U_b,     const float* __restrict__ A_W,
    const float* __restrict__ B_W,     const float* __restrict__ B_b,
    const float* __restrict__ out_W,   const float* __restrict__ out_b,
    float* __restrict__ out)
{
    // 31,616 B total -> 5 blocks/CU
    __shared__ __align__(16) unsigned X32[WROWS * STR]; // 29,952 B; later aliased by x_del + p buffers
    __shared__ __align__(16) float lsed[WROWS];         //    832 B (log2-domain lse)
    __shared__ __align__(16) float dbs_l[WROWS];        //    832 B (delay_b * log2e; -inf pad)

    const int tid  = threadIdx.x;
    const int wid  = tid >> 6;
    const int lane = tid & 63;
    const int q    = lane >> 4;     // quad 0..3
    const int n    = lane & 15;     // col-lane 0..15
    const int b    = blockIdx.x;
    const float* xb = x + (size_t)b * (S_ * C_);
    const unsigned* Whi = ws;
    const unsigned* Wlo = ws + WFRAG;
    const float* A2g = (const float*)(ws + 2 * WFRAG);
    const float* A4g = (const float*)(ws + 2 * WFRAG + 64);

    // ---- Phase 0: stage packed x rows (vectorized, cvt_pk) + delay_b into LDS ----
    for (int i = tid; i < WROWS * 9; i += 256) {
        int r = i / 9, cg = i - r * 9;        // cg: group of 4 dwords in the 36-dword row
        f32x4 v = {0.f, 0.f, 0.f, 0.f};
        if (r < S_) {
            if (cg < 6)       __builtin_memcpy(&v, &xb[r * C_ + cg * 4], 16); // c 0..23
            else if (cg == 6) v[0] = xb[r * C_ + 24];                          // c 24 (tail)
        }
        unsigned e0, e1, e2, e3;
        pack_hl2(v[0], v[1], e0, e1);
        pack_hl2(v[2], v[3], e2, e3);
        uint4v p = {e0, e1, e2, e3};
        *(uint4v*)&X32[r * STR + cg * 4] = p;
    }
    for (int i = tid; i < WROWS; i += 256)
        dbs_l[i] = (i < S_) ? delay_b[i] * 1.44269504088896340736f : -1e30f;
    __syncthreads();

    // ---- Pass 1: lse[t] (log2 domain) via MFMA. Wave owns t-strips wid, wid+4, ... ----
    for (int st = wid; st < NSTRIP; st += 4) {
        const int t = st * 16 + n;
        const uint4v* xp = (const uint4v*)&X32[t * STR + q * 8];
        Frag fa = build_frag8(xp[0], xp[1]);       // A[m=t][k=c]
        float rs0 = 0.f, rs1 = 0.f, rs2 = 0.f, rs3 = 0.f;
        for (int sv = 0; sv < NSTILE; ++sv) {
            Frag fb;                               // B[k=c][n=s], pre-laid-out fragments
            fb.hi = __builtin_bit_cast(bf16x8, *(const uint4v*)&Whi[(sv * 64 + lane) * 4]);
            fb.lo = __builtin_bit_cast(bf16x8, *(const uint4v*)&Wlo[(sv * 64 + lane) * 4]);
            f32x4 L = {0.f, 0.f, 0.f, 0.f};
            L = mfma_split(fa, fb, L);
            const float dbv = dbs_l[sv * 16 + n];  // = -1e30 for padded s -> exp2 = 0
            rs0 += fexp2(L[0] + dbv);
            rs1 += fexp2(L[1] + dbv);
            rs2 += fexp2(L[2] + dbv);
            rs3 += fexp2(L[3] + dbv);
        }
#pragma unroll
        for (int off = 1; off < 16; off <<= 1) {
            rs0 += __shfl_xor(rs0, off);
            rs1 += __shfl_xor(rs1, off);
            rs2 += __shfl_xor(rs2, off);
            rs3 += __shfl_xor(rs3, off);
        }
        if (n < 4) {
            float v = (n == 0) ? rs0 : (n == 1) ? rs1 : (n == 2) ? rs2 : rs3;
            lsed[st * 16 + q * 4 + n] = flog2(v);
        }
    }
    __syncthreads();

    // ---- Pass 2: x_del = P^T X via MFMA, strip pairs; P transpose fully in-register ----
    f32x4 acc[4][2];
#pragma unroll
    for (int i = 0; i < 4; ++i)
#pragma unroll
        for (int j = 0; j < 2; ++j) acc[i][j] = f32x4{0.f, 0.f, 0.f, 0.f};

    for (int pair = 0; pair < NPAIR; ++pair) {
        const int sA = 2 * pair, sB = sA + 1;
        const bool bval = (sB < NSTRIP);
        const uint4v* xpA = (const uint4v*)&X32[(sA * 16 + n) * STR + q * 8];
        Frag faA = build_frag8(xpA[0], xpA[1]);
        Frag faB;
        if (bval) {
            const uint4v* xpB = (const uint4v*)&X32[(sB * 16 + n) * STR + q * 8];
            faB = build_frag8(xpB[0], xpB[1]);
        }
        f32x4 lseA = *(const f32x4*)&lsed[sA * 16 + q * 4];
        f32x4 lseB = bval ? *(const f32x4*)&lsed[sB * 16 + q * 4] : f32x4{0,0,0,0};
        // B2 frags (hi only): B[k=t][n=c], t = pair*32 + q*8 + j
        bf16x8 b2h[2];
#pragma unroll
        for (int ct = 0; ct < 2; ++ct) {
            const int c = ct * 16 + n;
            uint4v d0, d1;
#pragma unroll
            for (int j = 0; j < 4; ++j) {
                int t2 = pair * 32 + q * 8 + j;
                ((unsigned*)&d0)[j] = (t2 < WROWS) ? X32[t2 * STR + c] : 0u;
            }
#pragma unroll
            for (int j = 0; j < 4; ++j) {
                int t2 = pair * 32 + q * 8 + 4 + j;
                ((unsigned*)&d1)[j] = (t2 < WROWS) ? X32[t2 * STR + c] : 0u;
            }
            b2h[ct] = build_hi8(d0, d1);
        }

#pragma unroll
        for (int si = 0; si < 4; ++si) {
            const int sv = wid + 4 * si;
            if (sv >= NSTILE) continue;          // wave-uniform branch
            Frag fb;
            fb.hi = __builtin_bit_cast(bf16x8, *(const uint4v*)&Whi[(sv * 64 + lane) * 4]);
            fb.lo = __builtin_bit_cast(bf16x8, *(const uint4v*)&Wlo[(sv * 64 + lane) * 4]);
            const float dbv = dbs_l[sv * 16 + n];
            // strip A logits -> P (hi/lo packed pairs, C-layout)
            unsigned pA0, pA1, qA0, qA1;
            {
                f32x4 L = {0.f, 0.f, 0.f, 0.f};
                L = mfma_split(faA, fb, L);
                float e0 = fexp2(L[0] + dbv - lseA[0]);
                float e1 = fexp2(L[1] + dbv - lseA[1]);
                float e2 = fexp2(L[2] + dbv - lseA[2]);
                float e3 = fexp2(L[3] + dbv - lseA[3]);
                pA0 = cvt_pk_bf16(e0, e1);
                pA1 = cvt_pk_bf16(e2, e3);
                qA0 = cvt_pk_bf16(e0 - lo16f(pA0), e1 - hi16f(pA0));
                qA1 = cvt_pk_bf16(e2 - lo16f(pA1), e3 - hi16f(pA1));
            }
            // strip B (or zeros)
            unsigned pB0 = 0u, pB1 = 0u, qB0 = 0u, qB1 = 0u;
            if (bval) {
                f32x4 L = {0.f, 0.f, 0.f, 0.f};
                L = mfma_split(faB, fb, L);
                float e0 = fexp2(L[0] + dbv - lseB[0]);
                float e1 = fexp2(L[1] + dbv - lseB[1]);
                float e2 = fexp2(L[2] + dbv - lseB[2]);
                float e3 = fexp2(L[3] + dbv - lseB[3]);
                pB0 = cvt_pk_bf16(e0, e1);
                pB1 = cvt_pk_bf16(e2, e3);
                qB0 = cvt_pk_bf16(e0 - lo16f(pB0), e1 - hi16f(pB0));
                qB1 = cvt_pk_bf16(e2 - lo16f(pB1), e3 - hi16f(pB1));
            }
            // in-register transpose to A-layout: A[m=s][k=t], k = q*8 + j
            xpose_quads(pA0, pA1, pB0, pB1);
            xpose_quads(qA0, qA1, qB0, qB1);
            uint4v hv = {pA0, pA1, pB0, pB1};
            uint4v lv = {qA0, qA1, qB0, qB1};
            bf16x8 a2h = __builtin_bit_cast(bf16x8, hv);
            bf16x8 a2l = __builtin_bit_cast(bf16x8, lv);
#pragma unroll
            for (int ct = 0; ct < 2; ++ct) {
                f32x4 c4 = acc[si][ct];
                c4 = mfma16(a2h, b2h[ct], c4);
                c4 = mfma16(a2l, b2h[ct], c4);
                acc[si][ct] = c4;
            }
        }
    }
    __syncthreads();   // all X32 reads done; safe to alias

    // ---- store x_del into reused LDS (float, stride XDS=28, 16B-aligned rows) ----
    float* xdelf = (float*)&X32[0];
    float* p_s   = (float*)&X32[5600];   // 200*8 floats, after x_del's 200*28=5600
#pragma unroll
    for (int si = 0; si < 4; ++si) {
        const int sv = wid + 4 * si;
        if (sv >= NSTILE) continue;
#pragma unroll
        for (int ct = 0; ct < 2; ++ct) {
            const int c = ct * 16 + n;
            if (c < C_) {
#pragma unroll
                for (int r = 0; r < 4; ++r) {
                    const int s = sv * 16 + q * 4 + r;
                    if (s < S_) xdelf[s * XDS + c] = acc[si][ct][r];
                }
            }
        }
    }
    __syncthreads();

    // ---- u / bgate epilogue: thread s owns output timestep s (b128 x_del reads) ----
    if (tid < S_) {
        const int s = tid;
        float a[24];
        const f32x4* ar = (const f32x4*)&xdelf[s * XDS];
#pragma unroll
        for (int k = 0; k < 6; ++k) *(f32x4*)&a[k * 4] = ar[k];
        float a24 = xdelf[s * XDS + 24];
#pragma unroll
        for (int h = 0; h < H_; ++h) {
            float uu = fmaf(a24, U_W[h * C_ + 24], U_b[h]);
            float bb = fmaf(a24, B_W[h * C_ + 24], B_b[h]);
#pragma unroll
            for (int i = 0; i < 24; ++i) {
                uu = fmaf(a[i], U_W[h * C_ + i], uu);
                bb = fmaf(a[i], B_W[h * C_ + i], bb);
            }
            float sg_ = 1.0f / (1.0f + __expf(-bb));
            p_s[s * H_ + h] = uu * sg_;
        }
    }
    __syncthreads();

    // ---- linear recurrence h_s = A h_{s-1} + p_s via 4-step parallel prefix ----
    float* p1 = xdelf;                   // alias: xdelf dead after u/bgate
    float* p2 = xdelf + S_ * H_;
    for (int i2 = tid; i2 < S_ * H_; i2 += 256) {
        const int s = i2 >> 3, i = i2 & 7;
        float v = p_s[i2];
        if (s > 0) {
            const float* pm = &p_s[(s - 1) * H_];
#pragma unroll
            for (int j = 0; j < H_; ++j) v = fmaf(A_W[i * H_ + j], pm[j], v);
        }
        p1[i2] = v;
    }
    __syncthreads();
    for (int i2 = tid; i2 < S_ * H_; i2 += 256) {
        const int s = i2 >> 3, i = i2 & 7;
        float v = p1[i2];
        if (s > 1) {
            const float* pm = &p1[(s - 2) * H_];
#pragma unroll
            for (int j = 0; j < H_; ++j) v = fmaf(A2g[i * H_ + j], pm[j], v);
        }
        p2[i2] = v;
    }
    __syncthreads();
    // 4 independent chains (s mod 4) of 50 steps each; 32 lanes of wave 0
    if (tid < 32) {
        const int r = tid >> 3, i = tid & 7;
        float A4r[H_];
#pragma unroll
        for (int j = 0; j < H_; ++j) A4r[j] = A4g[i * H_ + j];
        float h = 0.f;
        for (int k = 0; k < 50; ++k) {
            const int s = 4 * k + r;
            float v = p2[s * H_ + i];
#pragma unroll
            for (int j = 0; j < H_; ++j) v = fmaf(A4r[j], __shfl(h, j, 8), v);
            h = v;
            p_s[s * H_ + i] = h;
        }
    }
    __syncthreads();

    // ---- out[b,s,c] = hs[s]·out_W[c,:] + out_b[c] (vectorized loads) ----
    float* ob_ptr = out + (size_t)b * (S_ * C_);
    for (int i = tid; i < S_ * C_; i += 256) {
        int s = i / C_, c = i - s * C_;
        const f32x4* pr = (const f32x4*)&p_s[s * H_];
        const f32x4* wr = (const f32x4*)&out_W[c * H_];
        f32x4 h0 = pr[0], h1 = pr[1];
        f32x4 w0 = wr[0], w1 = wr[1];
        float v = out_b[c];
        v = fmaf(h0[0], w0[0], v);
        v = fmaf(h0[1], w0[1], v);
        v = fmaf(h0[2], w0[2], v);
        v = fmaf(h0[3], w0[3], v);
        v = fmaf(h1[0], w1[0], v);
        v = fmaf(h1[1], w1[1], v);
        v = fmaf(h1[2], w1[2], v);
        v = fmaf(h1[3], w1[3], v);
        ob_ptr[i] = v;
    }
}

extern "C" void kernel_launch(void* const* d_in, const int* in_sizes, int n_in,
                              void* d_out, int out_size, void* d_ws, size_t ws_size,
                              hipStream_t stream) {
    const float* x       = (const float*)d_in[0];
    const float* delay_W = (const float*)d_in[1];
    const float* delay_b = (const float*)d_in[2];
    const float* U_W     = (const float*)d_in[3];
    const float* U_b     = (const float*)d_in[4];
    const float* A_W     = (const float*)d_in[5];
    const float* B_W     = (const float*)d_in[6];
    const float* B_b     = (const float*)d_in[7];
    const float* out_W   = (const float*)d_in[8];
    const float* out_b   = (const float*)d_in[9];
    float* out = (float*)d_out;
    unsigned* ws = (unsigned*)d_ws;   // (2*3328 + 128) dwords = 27,136 B

    prep_w_kernel<<<4, 256, 0, stream>>>(delay_W, A_W, ws);
    ssm_syn_delay_kernel<<<NB, 256, 0, stream>>>(
        x, ws, delay_b, U_W, U_b, A_W, B_W, B_b, out_W, out_b, out);
}

// Round 6
// 231.874 us; speedup vs baseline: 1.6199x; 1.0135x over previous
//
#include <hip/hip_runtime.h>

#define NB 2048
#define S_ 200
#define C_ 25
#define H_ 8
#define WROWS 208        // padded row count for packed X rows
#define STR 36           // dword stride of packed rows (multiple of 4 -> b128-aligned)
#define NSTRIP 13        // ceil(200/16) t-strips
#define NSTILE 13        // ceil(200/16) s-tiles
#define NPAIR 7          // ceil(13/2) strip pairs (K=32 each)
#define XDS 28           // x_del float stride in reused LDS (16B-aligned rows)
#define WFRAG (13 * 64 * 4)   // 3328 dwords per W fragment plane

typedef __bf16   bf16x8 __attribute__((ext_vector_type(8)));
typedef float    f32x4  __attribute__((ext_vector_type(4)));
typedef unsigned uint4v __attribute__((ext_vector_type(4)));

struct Frag { bf16x8 hi, lo; };

__device__ __forceinline__ unsigned short f2bf(float f) {
    unsigned u = __builtin_bit_cast(unsigned, f);
    return (unsigned short)((u + 0x7FFFu + ((u >> 16) & 1u)) >> 16);
}
__device__ __forceinline__ float bfh2f(unsigned short h) {
    return __builtin_bit_cast(float, (unsigned)h << 16);
}
// pack one f32 into (hi bf16 | lo bf16 << 16)
__device__ __forceinline__ unsigned pack_hl(float v) {
    unsigned short h = f2bf(v);
    unsigned short l = f2bf(v - bfh2f(h));
    return (unsigned)h | ((unsigned)l << 16);
}
__device__ __forceinline__ unsigned hi_pair(unsigned d0, unsigned d1) {
    return (d0 & 0xFFFFu) | (d1 << 16);
}
__device__ __forceinline__ unsigned lo_pair(unsigned d0, unsigned d1) {
    return (d0 >> 16) | (d1 & 0xFFFF0000u);
}
__device__ __forceinline__ Frag build_frag8(uint4v d0, uint4v d1) {
    uint4v h, l;
    h.x = hi_pair(d0.x, d0.y); h.y = hi_pair(d0.z, d0.w);
    h.z = hi_pair(d1.x, d1.y); h.w = hi_pair(d1.z, d1.w);
    l.x = lo_pair(d0.x, d0.y); l.y = lo_pair(d0.z, d0.w);
    l.z = lo_pair(d1.x, d1.y); l.w = lo_pair(d1.z, d1.w);
    Frag f;
    f.hi = __builtin_bit_cast(bf16x8, h);
    f.lo = __builtin_bit_cast(bf16x8, l);
    return f;
}
__device__ __forceinline__ bf16x8 build_hi8(uint4v d0, uint4v d1) {
    uint4v h;
    h.x = hi_pair(d0.x, d0.y); h.y = hi_pair(d0.z, d0.w);
    h.z = hi_pair(d1.x, d1.y); h.w = hi_pair(d1.z, d1.w);
    return __builtin_bit_cast(bf16x8, h);
}
__device__ __forceinline__ f32x4 mfma16(bf16x8 a, bf16x8 b, f32x4 c) {
    return __builtin_amdgcn_mfma_f32_16x16x32_bf16(a, b, c, 0, 0, 0);
}
// split-precision D += A*B (drop lo*lo term)
__device__ __forceinline__ f32x4 mfma_split(const Frag& a, const Frag& b, f32x4 c) {
    c = mfma16(a.hi, b.hi, c);
    c = mfma16(a.hi, b.lo, c);
    c = mfma16(a.lo, b.hi, c);
    return c;
}
// raw transcendentals: v_exp_f32 is 2^x, v_log_f32 is log2(x)
__device__ __forceinline__ float fexp2(float x) {
    float r; asm("v_exp_f32 %0, %1" : "=v"(r) : "v"(x)); return r;
}
__device__ __forceinline__ float flog2(float x) {
    float r; asm("v_log_f32 %0, %1" : "=v"(r) : "v"(x)); return r;
}
// pack two f32 -> (bf16(lo) | bf16(hi)<<16), RNE (no builtin on gfx950)
__device__ __forceinline__ unsigned cvt_pk_bf16(float vlo, float vhi) {
    unsigned r; asm("v_cvt_pk_bf16_f32 %0, %1, %2" : "=v"(r) : "v"(vlo), "v"(vhi)); return r;
}
__device__ __forceinline__ float lo16f(unsigned p) { return __builtin_bit_cast(float, p << 16); }
__device__ __forceinline__ float hi16f(unsigned p) { return __builtin_bit_cast(float, p & 0xFFFF0000u); }
// pack two f32 into two per-value (hi|lo<<16) dwords via cvt_pk (cheaper than 2x pack_hl)
__device__ __forceinline__ void pack_hl2(float v0, float v1, unsigned& d0, unsigned& d1) {
    unsigned hp = cvt_pk_bf16(v0, v1);
    float r0 = v0 - lo16f(hp);
    float r1 = v1 - hi16f(hp);
    unsigned lp = cvt_pk_bf16(r0, r1);
    d0 = (hp & 0xFFFFu) | (lp << 16);
    d1 = (hp >> 16) | (lp & 0xFFFF0000u);
}

// In-register MFMA C-layout (rows on quads/regs) -> A-layout (k on quads) transpose.
__device__ __forceinline__ void xpose_quads(unsigned& a0, unsigned& a1,
                                            unsigned& b0, unsigned& b1) {
    asm("v_permlane32_swap_b32 %0, %1" : "+v"(a0), "+v"(b0));
    asm("v_permlane32_swap_b32 %0, %1" : "+v"(a1), "+v"(b1));
    asm("v_permlane16_swap_b32 %0, %1" : "+v"(a0), "+v"(b0));
    asm("v_permlane16_swap_b32 %0, %1" : "+v"(a1), "+v"(b1));
}

// B2 fragment gather (X^T columns). GUARD only needed for pair==6 (t2 can reach 223>=WROWS).
// Unguarded path: plain constant-stride LDS reads -> compiler merges into ds_read2_b32.
template<bool GUARD>
__device__ __forceinline__ void build_b2h(const unsigned* X32p, int pair, int q, int n,
                                          bf16x8 b2h[2]) {
#pragma unroll
    for (int ct = 0; ct < 2; ++ct) {
        const int c = ct * 16 + n;
        uint4v d0, d1;
#pragma unroll
        for (int j = 0; j < 4; ++j) {
            int t2 = pair * 32 + q * 8 + j;
            unsigned v;
            if (GUARD) v = (t2 < WROWS) ? X32p[t2 * STR + c] : 0u;
            else       v = X32p[t2 * STR + c];
            ((unsigned*)&d0)[j] = v;
        }
#pragma unroll
        for (int j = 0; j < 4; ++j) {
            int t2 = pair * 32 + q * 8 + 4 + j;
            unsigned v;
            if (GUARD) v = (t2 < WROWS) ? X32p[t2 * STR + c] : 0u;
            else       v = X32p[t2 * STR + c];
            ((unsigned*)&d1)[j] = v;
        }
        b2h[ct] = build_hi8(d0, d1);
    }
}

// ---------- prep kernel: W fragment planes (pre-scaled by log2e) + A^2, A^4, A^8 ----------
__global__ void prep_w_kernel(const float* __restrict__ delay_W,
                              const float* __restrict__ A_W,
                              unsigned* __restrict__ ws) {
    const float LOG2E = 1.44269504088896340736f;
    unsigned* Whi = ws;
    unsigned* Wlo = ws + WFRAG;
    for (int idx = blockIdx.x * 256 + threadIdx.x; idx < WFRAG; idx += gridDim.x * 256) {
        int d = idx & 3, lane = (idx >> 2) & 63, sv = idx >> 8;
        int q = lane >> 4, nn = lane & 15;
        int s  = sv * 16 + nn;
        int c0 = q * 8 + 2 * d;
        float v0 = (s < S_ && c0     < C_) ? delay_W[s * C_ + c0]     * LOG2E : 0.f;
        float v1 = (s < S_ && c0 + 1 < C_) ? delay_W[s * C_ + c0 + 1] * LOG2E : 0.f;
        unsigned short h0 = f2bf(v0), h1 = f2bf(v1);
        unsigned short l0 = f2bf(v0 - bfh2f(h0)), l1 = f2bf(v1 - bfh2f(h1));
        Whi[idx] = (unsigned)h0 | ((unsigned)h1 << 16);
        Wlo[idx] = (unsigned)l0 | ((unsigned)l1 << 16);
    }
    // A^2, A^4, A^8 for the 8-step parallel recurrence
    __shared__ float A2s[64];
    __shared__ float A4s[64];
    if (blockIdx.x == 0) {
        float* A2g = (float*)(ws + 2 * WFRAG);
        float* A4g = (float*)(ws + 2 * WFRAG + 64);
        float* A8g = (float*)(ws + 2 * WFRAG + 128);
        const int i = threadIdx.x >> 3, j = threadIdx.x & 7;
        if (threadIdx.x < 64) {
            float s = 0.f;
            for (int k = 0; k < 8; ++k) s = fmaf(A_W[i * 8 + k], A_W[k * 8 + j], s);
            A2s[threadIdx.x] = s; A2g[threadIdx.x] = s;
        }
        __syncthreads();
        if (threadIdx.x < 64) {
            float s = 0.f;
            for (int k = 0; k < 8; ++k) s = fmaf(A2s[i * 8 + k], A2s[k * 8 + j], s);
            A4s[threadIdx.x] = s; A4g[threadIdx.x] = s;
        }
        __syncthreads();
        if (threadIdx.x < 64) {
            float s = 0.f;
            for (int k = 0; k < 8; ++k) s = fmaf(A4s[i * 8 + k], A4s[k * 8 + j], s);
            A8g[threadIdx.x] = s;
        }
    }
}

// ---------- main kernel: one block per batch ----------
__global__ __launch_bounds__(256, 5) void ssm_syn_delay_kernel(
    const float* __restrict__ x,       const unsigned* __restrict__ ws,
    const float* __restrict__ delay_b, const float* __restrict__ U_W,
    const float* __restrict__ U_b,     const float* __restrict__ A_W,
    const float* __restrict__ B_W,     const float* __restrict__ B_b,
    const float* __restrict__ out_W,   const float* __restrict__ out_b,
    float* __restrict__ out)
{
    // 31,616 B total -> 5 blocks/CU
    __shared__ __align__(16) unsigned X32[WROWS * STR]; // 29,952 B; later aliased by x_del + p buffers
    __shared__ __align__(16) float lsed[WROWS];         //    832 B (log2-domain lse)
    __shared__ __align__(16) float dbs_l[WROWS];        //    832 B (delay_b * log2e; -inf pad)

    const int tid  = threadIdx.x;
    const int wid  = tid >> 6;
    const int lane = tid & 63;
    const int q    = lane >> 4;     // quad 0..3
    const int n    = lane & 15;     // col-lane 0..15
    const int b    = blockIdx.x;
    const float* xb = x + (size_t)b * (S_ * C_);
    const unsigned* Whi = ws;
    const unsigned* Wlo = ws + WFRAG;
    const float* A2g = (const float*)(ws + 2 * WFRAG);
    const float* A4g = (const float*)(ws + 2 * WFRAG + 64);
    const float* A8g = (const float*)(ws + 2 * WFRAG + 128);

    // ---- Phase 0: stage packed x rows (vectorized, cvt_pk) + delay_b into LDS ----
    for (int i = tid; i < WROWS * 9; i += 256) {
        int r = i / 9, cg = i - r * 9;        // cg: group of 4 dwords in the 36-dword row
        f32x4 v = {0.f, 0.f, 0.f, 0.f};
        if (r < S_) {
            if (cg < 6)       __builtin_memcpy(&v, &xb[r * C_ + cg * 4], 16); // c 0..23
            else if (cg == 6) v[0] = xb[r * C_ + 24];                          // c 24 (tail)
        }
        unsigned e0, e1, e2, e3;
        pack_hl2(v[0], v[1], e0, e1);
        pack_hl2(v[2], v[3], e2, e3);
        uint4v p = {e0, e1, e2, e3};
        *(uint4v*)&X32[r * STR + cg * 4] = p;
    }
    for (int i = tid; i < WROWS; i += 256)
        dbs_l[i] = (i < S_) ? delay_b[i] * 1.44269504088896340736f : -1e30f;
    __syncthreads();

    // ---- Pass 1: lse[t] (log2 domain) via MFMA. Wave owns t-strips wid, wid+4, ... ----
    for (int st = wid; st < NSTRIP; st += 4) {
        const int t = st * 16 + n;
        const uint4v* xp = (const uint4v*)&X32[t * STR + q * 8];
        Frag fa = build_frag8(xp[0], xp[1]);       // A[m=t][k=c]
        float rs0 = 0.f, rs1 = 0.f, rs2 = 0.f, rs3 = 0.f;
        for (int sv = 0; sv < NSTILE; ++sv) {
            Frag fb;                               // B[k=c][n=s], pre-laid-out fragments
            fb.hi = __builtin_bit_cast(bf16x8, *(const uint4v*)&Whi[(sv * 64 + lane) * 4]);
            fb.lo = __builtin_bit_cast(bf16x8, *(const uint4v*)&Wlo[(sv * 64 + lane) * 4]);
            f32x4 L = {0.f, 0.f, 0.f, 0.f};
            L = mfma_split(fa, fb, L);
            const float dbv = dbs_l[sv * 16 + n];  // = -1e30 for padded s -> exp2 = 0
            rs0 += fexp2(L[0] + dbv);
            rs1 += fexp2(L[1] + dbv);
            rs2 += fexp2(L[2] + dbv);
            rs3 += fexp2(L[3] + dbv);
        }
#pragma unroll
        for (int off = 1; off < 16; off <<= 1) {
            rs0 += __shfl_xor(rs0, off);
            rs1 += __shfl_xor(rs1, off);
            rs2 += __shfl_xor(rs2, off);
            rs3 += __shfl_xor(rs3, off);
        }
        if (n < 4) {
            float v = (n == 0) ? rs0 : (n == 1) ? rs1 : (n == 2) ? rs2 : rs3;
            lsed[st * 16 + q * 4 + n] = flog2(v);
        }
    }
    __syncthreads();

    // ---- Pass 2: x_del = P^T X via MFMA, strip pairs; P transpose fully in-register ----
    f32x4 acc[4][2];
#pragma unroll
    for (int i = 0; i < 4; ++i)
#pragma unroll
        for (int j = 0; j < 2; ++j) acc[i][j] = f32x4{0.f, 0.f, 0.f, 0.f};

    for (int pair = 0; pair < NPAIR; ++pair) {
        const int sA = 2 * pair, sB = sA + 1;
        const bool bval = (sB < NSTRIP);
        const uint4v* xpA = (const uint4v*)&X32[(sA * 16 + n) * STR + q * 8];
        Frag faA = build_frag8(xpA[0], xpA[1]);
        Frag faB;
        if (bval) {
            const uint4v* xpB = (const uint4v*)&X32[(sB * 16 + n) * STR + q * 8];
            faB = build_frag8(xpB[0], xpB[1]);
        }
        f32x4 lseA = *(const f32x4*)&lsed[sA * 16 + q * 4];
        f32x4 lseB = bval ? *(const f32x4*)&lsed[sB * 16 + q * 4] : f32x4{0,0,0,0};
        // B2 frags (hi only): B[k=t][n=c], t = pair*32 + q*8 + j
        bf16x8 b2h[2];
        if (pair < 6) build_b2h<false>(X32, pair, q, n, b2h);
        else          build_b2h<true >(X32, pair, q, n, b2h);

#pragma unroll
        for (int si = 0; si < 4; ++si) {
            const int sv = wid + 4 * si;
            if (sv >= NSTILE) continue;          // wave-uniform branch
            Frag fb;
            fb.hi = __builtin_bit_cast(bf16x8, *(const uint4v*)&Whi[(sv * 64 + lane) * 4]);
            fb.lo = __builtin_bit_cast(bf16x8, *(const uint4v*)&Wlo[(sv * 64 + lane) * 4]);
            const float dbv = dbs_l[sv * 16 + n];
            // strip A logits -> P (hi/lo packed pairs, C-layout)
            unsigned pA0, pA1, qA0, qA1;
            {
                f32x4 L = {0.f, 0.f, 0.f, 0.f};
                L = mfma_split(faA, fb, L);
                float e0 = fexp2(L[0] + dbv - lseA[0]);
                float e1 = fexp2(L[1] + dbv - lseA[1]);
                float e2 = fexp2(L[2] + dbv - lseA[2]);
                float e3 = fexp2(L[3] + dbv - lseA[3]);
                pA0 = cvt_pk_bf16(e0, e1);
                pA1 = cvt_pk_bf16(e2, e3);
                qA0 = cvt_pk_bf16(e0 - lo16f(pA0), e1 - hi16f(pA0));
                qA1 = cvt_pk_bf16(e2 - lo16f(pA1), e3 - hi16f(pA1));
            }
            // strip B (or zeros)
            unsigned pB0 = 0u, pB1 = 0u, qB0 = 0u, qB1 = 0u;
            if (bval) {
                f32x4 L = {0.f, 0.f, 0.f, 0.f};
                L = mfma_split(faB, fb, L);
                float e0 = fexp2(L[0] + dbv - lseB[0]);
                float e1 = fexp2(L[1] + dbv - lseB[1]);
                float e2 = fexp2(L[2] + dbv - lseB[2]);
                float e3 = fexp2(L[3] + dbv - lseB[3]);
                pB0 = cvt_pk_bf16(e0, e1);
                pB1 = cvt_pk_bf16(e2, e3);
                qB0 = cvt_pk_bf16(e0 - lo16f(pB0), e1 - hi16f(pB0));
                qB1 = cvt_pk_bf16(e2 - lo16f(pB1), e3 - hi16f(pB1));
            }
            // in-register transpose to A-layout: A[m=s][k=t], k = q*8 + j
            xpose_quads(pA0, pA1, pB0, pB1);
            xpose_quads(qA0, qA1, qB0, qB1);
            uint4v hv = {pA0, pA1, pB0, pB1};
            uint4v lv = {qA0, qA1, qB0, qB1};
            bf16x8 a2h = __builtin_bit_cast(bf16x8, hv);
            bf16x8 a2l = __builtin_bit_cast(bf16x8, lv);
#pragma unroll
            for (int ct = 0; ct < 2; ++ct) {
                f32x4 c4 = acc[si][ct];
                c4 = mfma16(a2h, b2h[ct], c4);
                c4 = mfma16(a2l, b2h[ct], c4);
                acc[si][ct] = c4;
            }
        }
    }
    __syncthreads();   // all X32 reads done; safe to alias

    // ---- store x_del into reused LDS (float, stride XDS=28, 16B-aligned rows) ----
    float* xdelf = (float*)&X32[0];
    float* p_s   = (float*)&X32[5600];   // 200*8 floats, after x_del's 200*28=5600
#pragma unroll
    for (int si = 0; si < 4; ++si) {
        const int sv = wid + 4 * si;
        if (sv >= NSTILE) continue;
#pragma unroll
        for (int ct = 0; ct < 2; ++ct) {
            const int c = ct * 16 + n;
            if (c < C_) {
#pragma unroll
                for (int r = 0; r < 4; ++r) {
                    const int s = sv * 16 + q * 4 + r;
                    if (s < S_) xdelf[s * XDS + c] = acc[si][ct][r];
                }
            }
        }
    }
    __syncthreads();

    // ---- u / bgate epilogue: thread s owns output timestep s (b128 x_del reads) ----
    if (tid < S_) {
        const int s = tid;
        float a[24];
        const f32x4* ar = (const f32x4*)&xdelf[s * XDS];
#pragma unroll
        for (int k = 0; k < 6; ++k) *(f32x4*)&a[k * 4] = ar[k];
        float a24 = xdelf[s * XDS + 24];
#pragma unroll
        for (int h = 0; h < H_; ++h) {
            float uu = fmaf(a24, U_W[h * C_ + 24], U_b[h]);
            float bb = fmaf(a24, B_W[h * C_ + 24], B_b[h]);
#pragma unroll
            for (int i = 0; i < 24; ++i) {
                uu = fmaf(a[i], U_W[h * C_ + i], uu);
                bb = fmaf(a[i], B_W[h * C_ + i], bb);
            }
            float sg_ = 1.0f / (1.0f + __expf(-bb));
            p_s[s * H_ + h] = uu * sg_;
        }
    }
    __syncthreads();

    // ---- linear recurrence h_s = A h_{s-1} + p_s via 8-step parallel prefix ----
    float* p1 = xdelf;                   // alias: xdelf dead after u/bgate (1600 floats)
    float* p2 = xdelf + 1600;
    float* p4 = xdelf + 3200;
    for (int i2 = tid; i2 < S_ * H_; i2 += 256) {
        const int s = i2 >> 3, i = i2 & 7;
        float v = p_s[i2];
        if (s > 0) {
            const float* pm = &p_s[(s - 1) * H_];
#pragma unroll
            for (int j = 0; j < H_; ++j) v = fmaf(A_W[i * H_ + j], pm[j], v);
        }
        p1[i2] = v;
    }
    __syncthreads();
    for (int i2 = tid; i2 < S_ * H_; i2 += 256) {
        const int s = i2 >> 3, i = i2 & 7;
        float v = p1[i2];
        if (s > 1) {
            const float* pm = &p1[(s - 2) * H_];
#pragma unroll
            for (int j = 0; j < H_; ++j) v = fmaf(A2g[i * H_ + j], pm[j], v);
        }
        p2[i2] = v;
    }
    __syncthreads();
    for (int i2 = tid; i2 < S_ * H_; i2 += 256) {
        const int s = i2 >> 3, i = i2 & 7;
        float v = p2[i2];
        if (s > 3) {
            const float* pm = &p2[(s - 4) * H_];
#pragma unroll
            for (int j = 0; j < H_; ++j) v = fmaf(A4g[i * H_ + j], pm[j], v);
        }
        p4[i2] = v;
    }
    __syncthreads();
    // 8 independent chains (s mod 8) of 25 steps each; 64 lanes of wave 0
    if (tid < 64) {
        const int r = tid >> 3, i = tid & 7;
        float A8r[H_];
#pragma unroll
        for (int j = 0; j < H_; ++j) A8r[j] = A8g[i * H_ + j];
        float h = 0.f;
        for (int k = 0; k < 25; ++k) {
            const int s = 8 * k + r;
            float v = p4[s * H_ + i];
#pragma unroll
            for (int j = 0; j < H_; ++j) v = fmaf(A8r[j], __shfl(h, j, 8), v);
            h = v;
            p_s[s * H_ + i] = h;
        }
    }
    __syncthreads();

    // ---- out[b,s,c] = hs[s]·out_W[c,:] + out_b[c] (vectorized loads) ----
    float* ob_ptr = out + (size_t)b * (S_ * C_);
    for (int i = tid; i < S_ * C_; i += 256) {
        int s = i / C_, c = i - s * C_;
        const f32x4* pr = (const f32x4*)&p_s[s * H_];
        const f32x4* wr = (const f32x4*)&out_W[c * H_];
        f32x4 h0 = pr[0], h1 = pr[1];
        f32x4 w0 = wr[0], w1 = wr[1];
        float v = out_b[c];
        v = fmaf(h0[0], w0[0], v);
        v = fmaf(h0[1], w0[1], v);
        v = fmaf(h0[2], w0[2], v);
        v = fmaf(h0[3], w0[3], v);
        v = fmaf(h1[0], w1[0], v);
        v = fmaf(h1[1], w1[1], v);
        v = fmaf(h1[2], w1[2], v);
        v = fmaf(h1[3], w1[3], v);
        ob_ptr[i] = v;
    }
}

extern "C" void kernel_launch(void* const* d_in, const int* in_sizes, int n_in,
                              void* d_out, int out_size, void* d_ws, size_t ws_size,
                              hipStream_t stream) {
    const float* x       = (const float*)d_in[0];
    const float* delay_W = (const float*)d_in[1];
    const float* delay_b = (const float*)d_in[2];
    const float* U_W     = (const float*)d_in[3];
    const float* U_b     = (const float*)d_in[4];
    const float* A_W     = (const float*)d_in[5];
    const float* B_W     = (const float*)d_in[6];
    const float* B_b     = (const float*)d_in[7];
    const float* out_W   = (const float*)d_in[8];
    const float* out_b   = (const float*)d_in[9];
    float* out = (float*)d_out;
    unsigned* ws = (unsigned*)d_ws;   // (2*3328 + 192) dwords = 27,392 B

    prep_w_kernel<<<4, 256, 0, stream>>>(delay_W, A_W, ws);
    ssm_syn_delay_kernel<<<NB, 256, 0, stream>>>(
        x, ws, delay_b, U_W, U_b, A_W, B_W, B_b, out_W, out_b, out);
}